// Round 3
// baseline (825.077 us; speedup 1.0000x reference)
//
#include <hip/hip_runtime.h>

// AttentionDecoder: B=65536, T=10, E=64, H=64, D=5
// One wave owns 16 batch rows end-to-end; no inter-wave sync in the step loop.
// R2/R3: ep/xfo pinned in AGPRs (spill fix); online no-max softmax; DPP
// allreduce; y_tilde via 3rd MFMA; biases folded into MFMA acc init.
// R4: score fold (drop softmax-invariant const); v_cvt_pk_bf16_f32; y-proj
// hoisted out of step loop; preloop 1-deep global prefetch.
// R5 (REVERTED): exp2(ac+ep)=exp2(ac)*exp2(ep) factorization NaN'd; unexplained
// (suspect: v_exp_f32 result consumed directly by inline-asm cvt_pk -- new
// hazard pattern). Numerics restored to R4 bit-exact.
// R6 (this round): latency-structure change, zero numeric change --
//  (a) gates W_hh MFMA hoist: the 32 of 48 gate MFMAs that depend only on
//      ht (fa0/fa1, available at step start) issue BEFORE the softmax chain;
//      their LDS reads + MFMA latency overlap softmax VALU/trans (separate
//      pipes). Only the y_tilde MFMA (+LSTM) remains post-fence. Accumulation
//      order unchanged -> bit-identical.
//  (b) gate-bias BGC LDS reads hoisted to 16 per-lane registers (bgr).

#define DEVFN __device__ __forceinline__

typedef __attribute__((ext_vector_type(8))) short short8;
typedef __attribute__((ext_vector_type(4))) float f32x4;
typedef __attribute__((ext_vector_type(4))) int int4v;

DEVFN unsigned bfr(float f) {  // f32 -> bf16 bits, round-to-nearest-even
  unsigned u = __float_as_uint(f);
  return (u + 0x7fffu + ((u >> 16) & 1u)) >> 16;
}
// HW packed f32->bf16 (RTNE): dst.lo = bf16(lo), dst.hi = bf16(hi)
DEVFN unsigned cpk(float lo, float hi) {
  unsigned r;
  asm("v_cvt_pk_bf16_f32 %0, %1, %2" : "=v"(r) : "v"(lo), "v"(hi));
  return r;
}
DEVFN float ulo(unsigned p) { return __uint_as_float(p << 16); }
DEVFN float uhi(unsigned p) { return __uint_as_float(p & 0xffff0000u); }

// AGPR pinning: cold per-lane state lives in the otherwise-idle AGPR half.
DEVFN void awr(unsigned &a, unsigned v) {
  asm("v_accvgpr_write_b32 %0, %1" : "=a"(a) : "v"(v));
}
DEVFN unsigned ard(const unsigned &a) {
  unsigned v;
  asm("v_accvgpr_read_b32 %0, %1" : "=v"(v) : "a"(a));
  return v;
}

// 16-lane all-reduce sum, pure VALU (DPP), no LGKM traffic.
template <int CTRL>
DEVFN float dppadd(float v) {
  int t = __builtin_amdgcn_update_dpp(0, __float_as_int(v), CTRL, 0xf, 0xf, true);
  return v + __int_as_float(t);
}
DEVFN float sum16(float v) {
  v = dppadd<0xB1>(v);   // quad_perm(1,0,3,2)
  v = dppadd<0x4E>(v);   // quad_perm(2,3,0,1)
  v = dppadd<0x124>(v);  // row_ror:4
  v = dppadd<0x128>(v);  // row_ror:8
  return v;
}

// wave-internal LDS fence (cross-lane exchange within one wave).
DEVFN void lds_fence() {
  __builtin_amdgcn_wave_barrier();
  asm volatile("s_waitcnt lgkmcnt(0)" ::: "memory");
  __builtin_amdgcn_wave_barrier();
}

#define MFMA(a, b, c) __builtin_amdgcn_mfma_f32_16x16x32_bf16((a), (b), (c), 0, 0, 0)
#define EXP2(x) __builtin_amdgcn_exp2f(x)
#define RCP(x)  __builtin_amdgcn_rcpf(x)

// ---- LDS layout (bytes) ----
#define OFF_BHCT 0       // [64][136] bf16: W1_hc rows (e) x (j=0..127), *2log2e
#define OFF_BHHT 17408   // [256][72] bf16: W_hh rows (i) x (h), gate-scaled
#define OFF_BENC 54272   // [64][72]  bf16: W1_enc rows (e) x (d), *2log2e
#define OFF_BPRJ 63488   // [16][72]  bf16: n<5: fc_w[n][0:64]; n in 8..12: fco_w[n-8][64:128]
#define OFF_BIH  65792   // [256][40] bf16: W_ih gate-scaled in cols 0..4, zeros 5..31
#define OFF_BGC  86272   // [256]     f32 : (b_ih+b_hh) gate-scaled
#define OFF_FCO  87296   // [5][64]   f32 : fco_w[:, :64]
#define OFF_PW   88576   // per-wave regions
#define PWSZ     8832    //   +0: SCR [16][136] bf16 (x-tile staging, then hc)
                         //   +4352: YH [16][50] f32 (y tile, then yproj in place)
                         //   +7552: YTA [16][40] bf16 (y_tilde in A-layout)
#define SMEM_BYTES (OFF_PW + 8 * PWSZ)  // 159232

__global__ __launch_bounds__(512, 2) void attn_dec(
    const float* __restrict__ xg,   const float* __restrict__ yg,
    const float* __restrict__ h0,   const float* __restrict__ c0,
    const float* __restrict__ w1,   const float* __restrict__ b1g,
    const float* __restrict__ w2g,  const float* __restrict__ b2g,
    const float* __restrict__ wihg, const float* __restrict__ whhg,
    const float* __restrict__ bihg, const float* __restrict__ bhhg,
    const float* __restrict__ fcwg, const float* __restrict__ fcbg,
    const float* __restrict__ fcowg, const float* __restrict__ fcobg,
    float* __restrict__ outg) {
  (void)b2g;  // constant across t -> softmax-invariant
  extern __shared__ char smem[];
  unsigned short* BHCT = (unsigned short*)(smem + OFF_BHCT);
  unsigned short* BHHT = (unsigned short*)(smem + OFF_BHHT);
  unsigned short* BENC = (unsigned short*)(smem + OFF_BENC);
  unsigned short* BPRJ = (unsigned short*)(smem + OFF_BPRJ);
  unsigned short* BIH  = (unsigned short*)(smem + OFF_BIH);
  float* BGC  = (float*)(smem + OFF_BGC);
  float* FCOL = (float*)(smem + OFF_FCO);

  const int tid = threadIdx.x;
  const int wave = tid >> 6, lane = tid & 63;
  const int q = lane >> 4, m = lane & 15;
  const int rb = blockIdx.x * 128 + wave * 16;

  const float S2  = 2.88539008177792681f;   // 2*log2(e)
  const float NL  = -1.44269504088896341f;  // -log2(e)
  const float L2E = 1.44269504088896341f;

  unsigned short* SCR = (unsigned short*)(smem + OFF_PW + wave * PWSZ);
  float* YH = (float*)(smem + OFF_PW + wave * PWSZ + 4352);
  unsigned short* YTA = (unsigned short*)(smem + OFF_PW + wave * PWSZ + 7552);

  // ---------- cooperative shared-weight staging ----------
  for (int idx = tid; idx < 64 * 192; idx += 512) {
    int e = idx / 192, j = idx - e * 192;
    float v = w1[idx] * S2;
    if (j < 128) BHCT[e * 136 + j] = (unsigned short)bfr(v);
    else         BENC[e * 72 + (j - 128)] = (unsigned short)bfr(v);
  }
  for (int idx = tid; idx < 256 * 64; idx += 512) {
    int i = idx >> 6;
    float s = (i >= 128 && i < 192) ? S2 : NL;
    BHHT[i * 72 + (idx & 63)] = (unsigned short)bfr(whhg[idx] * s);
  }
  for (int idx = tid; idx < 16 * 64; idx += 512) {
    int n = idx >> 6, d = idx & 63;
    float v = 0.f;
    if (n < 5) v = fcwg[n * 69 + d];
    else if (n >= 8 && n < 13) v = fcowg[(n - 8) * 128 + 64 + d];
    BPRJ[n * 72 + d] = (unsigned short)bfr(v);
  }
  for (int idx = tid; idx < 256 * 32; idx += 512) {
    int n = idx >> 5, k = idx & 31;
    float s = (n >= 128 && n < 192) ? S2 : NL;
    float v = (k < 5) ? wihg[n * 5 + k] * s : 0.f;
    BIH[n * 40 + k] = (unsigned short)bfr(v);
  }
  for (int idx = tid; idx < 256; idx += 512) {
    float s = (idx >= 128 && idx < 192) ? S2 : NL;
    BGC[idx] = (bihg[idx] + bhhg[idx]) * s;
  }
  for (int idx = tid; idx < 5 * 64; idx += 512) {
    int d = idx >> 6, h = idx & 63;
    FCOL[idx] = fcowg[d * 128 + h];
  }
  __syncthreads();

  // ---------- per-wave: YH tile + YTA zero ----------
  for (int idx = lane; idx < 800; idx += 64) {
    int r = idx / 50, c = idx - r * 50;
    YH[idx] = yg[(size_t)(rb + r) * 50 + c];
  }
  for (int idx = lane; idx < 512; idx += 64)
    YTA[(idx >> 5) * 40 + (idx & 31)] = 0;
  lds_fence();

  // ---------- y-projection hoist: YH[row][t*5+n] <- fcb[n] + sum_j fcw[n][64+j]*y ----------
  {
    float fw[5][5], fb5[5];
#pragma unroll
    for (int n = 0; n < 5; ++n) {
      fb5[n] = fcbg[n];
#pragma unroll
      for (int j = 0; j < 5; ++j) fw[n][j] = fcwg[n * 69 + 64 + j];
    }
    for (int idx = lane; idx < 160; idx += 64) {
      int row = idx / 10, t = idx - row * 10;
      float yv[5];
#pragma unroll
      for (int j = 0; j < 5; ++j) yv[j] = YH[row * 50 + t * 5 + j];
#pragma unroll
      for (int n = 0; n < 5; ++n) {
        float v = fb5[n];
#pragma unroll
        for (int j = 0; j < 5; ++j) v = fmaf(fw[n][j], yv[j], v);
        YH[row * 50 + t * 5 + n] = v;
      }
    }
  }

  // ---------- per-lane constants ----------
  float b1e[4], w2n[4];
#pragma unroll
  for (int et = 0; et < 4; ++et) {
    b1e[et] = b1g[et * 16 + m] * S2;
    // score fold: p' accumulates (-2*w*log2e)*rcp(exp2(x)+1); the constant
    // sum_e w*log2e part of w*tanh is global -> cancels in softmax.
    w2n[et] = w2g[et * 16 + m] * (-2.f * L2E);
  }
  const int mc = (m < 5) ? m : 4;
  const float fcobv = fcobg[mc];
  float bgr[16];  // hoisted gate biases: bgr[hg*4+g] = BGC[g*64+hg*16+m]
#pragma unroll
  for (int hg = 0; hg < 4; ++hg)
#pragma unroll
    for (int g = 0; g < 4; ++g) bgr[hg * 4 + g] = BGC[g * 64 + hg * 16 + m];

  // ---------- pre-loop: enc_proj + xf/xo projections -> AGPRs ----------
  unsigned ep[10][4][2];  // [t][e-tile][row-pair] packed bf16, *2log2e  (AGPR)
  unsigned xfo[10][2];    // [t][row-pair]: col m<5 -> xf_d; col 8..12 -> xo  (AGPR)
  {
    const int rl = lane >> 2, cc = lane & 3;
    const float4* xpb = (const float4*)(xg + (size_t)(rb + rl) * 640);
    float4 v0 = xpb[cc * 4 + 0], v1 = xpb[cc * 4 + 1],
           v2 = xpb[cc * 4 + 2], v3 = xpb[cc * 4 + 3];
#pragma unroll
    for (int t = 0; t < 10; ++t) {
      lds_fence();  // WAR vs previous iteration's A-frag reads
      int4v d0, d1;
      d0.x = (int)cpk(v0.x, v0.y); d0.y = (int)cpk(v0.z, v0.w);
      d0.z = (int)cpk(v1.x, v1.y); d0.w = (int)cpk(v1.z, v1.w);
      d1.x = (int)cpk(v2.x, v2.y); d1.y = (int)cpk(v2.z, v2.w);
      d1.z = (int)cpk(v3.x, v3.y); d1.w = (int)cpk(v3.z, v3.w);
      *(int4v*)(SCR + rl * 72 + cc * 16) = d0;
      *(int4v*)(SCR + rl * 72 + cc * 16 + 8) = d1;
      lds_fence();
      if (t < 9) {  // software pipeline: next x-tile loads fly under the MFMAs
        v0 = xpb[(t + 1) * 16 + cc * 4 + 0];
        v1 = xpb[(t + 1) * 16 + cc * 4 + 1];
        v2 = xpb[(t + 1) * 16 + cc * 4 + 2];
        v3 = xpb[(t + 1) * 16 + cc * 4 + 3];
      }
      short8 xa0 = *(const short8*)(SCR + m * 72 + q * 8);
      short8 xa1 = *(const short8*)(SCR + m * 72 + 32 + q * 8);
#pragma unroll
      for (int et = 0; et < 4; ++et) {
        f32x4 acc = {0.f, 0.f, 0.f, 0.f};
        const unsigned short* bp = BENC + (et * 16 + m) * 72 + q * 8;
        acc = MFMA(xa0, *(const short8*)bp, acc);
        acc = MFMA(xa1, *(const short8*)(bp + 32), acc);
        awr(ep[t][et][0], cpk(acc[0], acc[1]));
        awr(ep[t][et][1], cpk(acc[2], acc[3]));
      }
      {
        f32x4 acc = {0.f, 0.f, 0.f, 0.f};
        const unsigned short* bp = BPRJ + m * 72 + q * 8;
        acc = MFMA(xa0, *(const short8*)bp, acc);
        acc = MFMA(xa1, *(const short8*)(bp + 32), acc);
        awr(xfo[t][0], cpk(acc[0], acc[1]));
        awr(xfo[t][1], cpk(acc[2], acc[3]));
      }
    }
  }

  // ---------- init state: ct f32 regs; [ht|ct] bf16 in SCR ----------
  float ctr[16];  // [hg*4 + r]
  lds_fence();
#pragma unroll
  for (int hg = 0; hg < 4; ++hg)
#pragma unroll
    for (int r = 0; r < 4; ++r) {
      int row = q * 4 + r, h = hg * 16 + m;
      float hv = h0[(size_t)(rb + row) * 64 + h];
      float cv = c0[(size_t)(rb + row) * 64 + h];
      ctr[hg * 4 + r] = cv;
      unsigned pk = cpk(hv, cv);
      SCR[row * 136 + h] = (unsigned short)pk;
      SCR[row * 136 + 64 + h] = (unsigned short)(pk >> 16);
    }
  lds_fence();

  // ---------- step loop ----------
  float yc[4] = {0.f, 0.f, 0.f, 0.f};
#pragma unroll 1
  for (int s = 0; s < 10; ++s) {
    // A) attn matvec: [ht|ct] @ W1_hc^T (+b1 folded into acc init)
    short8 fa0 = *(const short8*)(SCR + m * 136 + q * 8);
    short8 fa1 = *(const short8*)(SCR + m * 136 + 32 + q * 8);
    short8 fa2 = *(const short8*)(SCR + m * 136 + 64 + q * 8);
    short8 fa3 = *(const short8*)(SCR + m * 136 + 96 + q * 8);
    f32x4 ac4[4];
#pragma unroll
    for (int et = 0; et < 4; ++et) {
      f32x4 acc = {b1e[et], b1e[et], b1e[et], b1e[et]};
      const unsigned short* bp = BHCT + (et * 16 + m) * 136 + q * 8;
      acc = MFMA(fa0, *(const short8*)bp, acc);
      acc = MFMA(fa1, *(const short8*)(bp + 32), acc);
      acc = MFMA(fa2, *(const short8*)(bp + 64), acc);
      acc = MFMA(fa3, *(const short8*)(bp + 96), acc);
      ac4[et] = acc;
    }
    // F-early) gates W_hh portion: depends only on fa0/fa1 (ht), so issue
    // NOW -- the 32 MFMAs + their LDS reads run on the MFMA/LDS pipes while
    // the softmax VALU/trans chain below executes. Same accumulation order
    // as before (bias, fa0, fa1, [ay later]) -> bit-identical results.
    f32x4 gacc[16];
#pragma unroll
    for (int hg = 0; hg < 4; ++hg)
#pragma unroll
      for (int g = 0; g < 4; ++g) {
        int n = g * 64 + hg * 16 + m;
        float bg = bgr[hg * 4 + g];
        f32x4 acc = {bg, bg, bg, bg};
        const unsigned short* bp = BHHT + n * 72 + q * 8;
        acc = MFMA(fa0, *(const short8*)bp, acc);
        acc = MFMA(fa1, *(const short8*)(bp + 32), acc);
        gacc[hg * 4 + g] = acc;
      }
    // B/C/D) scores + online (no-max) softmax + context contraction.
    // p' = sum_e (-2 w log2e) * rcp(exp2(x)+1); dropped constant sum_e w
    // is softmax-invariant. |p'| <= 2*sum|w|*log2e ~ 23 -> exp2 f32-safe.
    float sm0 = 0.f, sm1 = 0.f, sm2 = 0.f, sm3 = 0.f;
    float cx0 = 0.f, cx1 = 0.f, cx2 = 0.f, cx3 = 0.f;
#pragma unroll
    for (int t = 0; t < 10; ++t) {
      float p0 = 0.f, p1 = 0.f, p2 = 0.f, p3 = 0.f;
#pragma unroll
      for (int et = 0; et < 4; ++et) {
        unsigned plo = ard(ep[t][et][0]), phi = ard(ep[t][et][1]);
        float x0 = ac4[et][0] + ulo(plo);
        float x1 = ac4[et][1] + uhi(plo);
        float x2 = ac4[et][2] + ulo(phi);
        float x3 = ac4[et][3] + uhi(phi);
        float r0 = RCP(EXP2(x0) + 1.f);
        float r1 = RCP(EXP2(x1) + 1.f);
        float r2 = RCP(EXP2(x2) + 1.f);
        float r3 = RCP(EXP2(x3) + 1.f);
        float w = w2n[et];
        p0 = fmaf(w, r0, p0); p1 = fmaf(w, r1, p1);
        p2 = fmaf(w, r2, p2); p3 = fmaf(w, r3, p3);
      }
      p0 = sum16(p0); p1 = sum16(p1); p2 = sum16(p2); p3 = sum16(p3);
      float e0 = EXP2(p0);
      float e1 = EXP2(p1);
      float e2 = EXP2(p2);
      float e3 = EXP2(p3);
      sm0 += e0; sm1 += e1; sm2 += e2; sm3 += e3;
      unsigned xl = ard(xfo[t][0]), xh = ard(xfo[t][1]);
      cx0 = fmaf(e0, ulo(xl), cx0);
      cx1 = fmaf(e1, uhi(xl), cx1);
      cx2 = fmaf(e2, ulo(xh), cx2);
      cx3 = fmaf(e3, uhi(xh), cx3);
    }
    yc[0] = cx0 * RCP(sm0);
    yc[1] = cx1 * RCP(sm1);
    yc[2] = cx2 * RCP(sm2);
    yc[3] = cx3 * RCP(sm3);
    // E) y_tilde -> YTA (A-layout rows, bf16); y-part precomputed in YH
#pragma unroll
    for (int r = 0; r < 4; ++r) {
      int row = q * 4 + r;
      float v = yc[r] + YH[row * 50 + s * 5 + mc];
      if (m < 5) YTA[row * 40 + m] = (unsigned short)cpk(v, v);
    }
    lds_fence();
    // F/G) finish gates with the y_tilde MFMA; LSTM update
    short8 ay = *(const short8*)(YTA + m * 40 + q * 8);
#pragma unroll
    for (int hg = 0; hg < 4; ++hg) {
      float ga[4][4];
#pragma unroll
      for (int g = 0; g < 4; ++g) {
        int n = g * 64 + hg * 16 + m;
        f32x4 acc = MFMA(ay, *(const short8*)(BIH + n * 40 + q * 8), gacc[hg * 4 + g]);
        ga[g][0] = acc[0]; ga[g][1] = acc[1]; ga[g][2] = acc[2]; ga[g][3] = acc[3];
      }
#pragma unroll
      for (int r = 0; r < 4; ++r) {
        float iv = RCP(1.f + EXP2(ga[0][r]));
        float fv = RCP(1.f + EXP2(ga[1][r]));
        float gv = fmaf(-2.f, RCP(EXP2(ga[2][r]) + 1.f), 1.f);
        float ov = RCP(1.f + EXP2(ga[3][r]));
        float c = fmaf(fv, ctr[hg * 4 + r], iv * gv);
        ctr[hg * 4 + r] = c;
        float th = fmaf(-2.f, RCP(EXP2(c * S2) + 1.f), 1.f);
        float hv = ov * th;
        int row = q * 4 + r, h = hg * 16 + m;
        unsigned pk = cpk(hv, c);
        SCR[row * 136 + h] = (unsigned short)pk;
        SCR[row * 136 + 64 + h] = (unsigned short)(pk >> 16);
      }
    }
    lds_fence();
  }

  // ---------- output: out = [ht, context] @ fco_w^T + fco_b ----------
#pragma unroll
  for (int r = 0; r < 4; ++r) {
    int row = q * 4 + r;
    float sum = fcobv + __shfl(yc[r], (lane & 48) + 8 + mc);
#pragma unroll
    for (int hq = 0; hq < 8; ++hq) {
      int4v hv = *(const int4v*)(SCR + row * 136 + hq * 8);
      const float* fp = FCOL + mc * 64 + hq * 8;
      sum += fp[0] * ulo((unsigned)hv.x) + fp[1] * uhi((unsigned)hv.x)
           + fp[2] * ulo((unsigned)hv.y) + fp[3] * uhi((unsigned)hv.y)
           + fp[4] * ulo((unsigned)hv.z) + fp[5] * uhi((unsigned)hv.z)
           + fp[6] * ulo((unsigned)hv.w) + fp[7] * uhi((unsigned)hv.w);
    }
    if (m < 5) outg[(size_t)(rb + row) * 5 + m] = sum;
  }
}

extern "C" void kernel_launch(void* const* d_in, const int* in_sizes, int n_in,
                              void* d_out, int out_size, void* d_ws, size_t ws_size,
                              hipStream_t stream) {
  (void)in_sizes; (void)n_in; (void)d_ws; (void)ws_size; (void)out_size;
  (void)hipFuncSetAttribute((const void*)attn_dec,
                            hipFuncAttributeMaxDynamicSharedMemorySize, SMEM_BYTES);
  attn_dec<<<dim3(512), dim3(512), SMEM_BYTES, stream>>>(
      (const float*)d_in[0], (const float*)d_in[1], (const float*)d_in[2],
      (const float*)d_in[3], (const float*)d_in[4], (const float*)d_in[5],
      (const float*)d_in[6], (const float*)d_in[7], (const float*)d_in[8],
      (const float*)d_in[9], (const float*)d_in[10], (const float*)d_in[11],
      (const float*)d_in[12], (const float*)d_in[13], (const float*)d_in[14],
      (const float*)d_in[15], (float*)d_out);
}

// Round 4
// 527.032 us; speedup vs baseline: 1.5655x; 1.5655x over previous
//
#include <hip/hip_runtime.h>

// AttentionDecoder: B=65536, T=10, E=64, H=64, D=5
// One wave owns 16 batch rows end-to-end; no inter-wave sync in the step loop.
// R2/R3: ep/xfo pinned in AGPRs (spill fix); online no-max softmax; DPP
// allreduce; y_tilde via 3rd MFMA; biases folded into MFMA acc init.
// R4: score fold (drop softmax-invariant const); v_cvt_pk_bf16_f32; y-proj
// hoisted out of step loop; preloop 1-deep global prefetch.
// R5 (FAILED NaN): exp2 factorization with EXP2 -> inline-asm cvt_pk in
// preloop. Diagnosis: trans->INLINEASM consumer wait-state not inserted.
// R6 (REGRESSED 637us): gacc[16] hoist spilled (128 VGPR + 100 AGPR + 64
// > 256 unified-file budget @ 2 waves/SIMD). WRITE_SIZE 3->88 MB. Reverted.
// Lesson: occupancy is register-locked at 2 waves/SIMD; only serial-path
// cuts can win.
// R7 (this round): R4 + bgr hoist + HAZARD-SAFE exp2 factorization:
//  - preloop stores E = exp2(ep) packed via SOFTWARE bfr/pk2 (compiler VALU
//    consumes the trans result -> hazard handled), NOT asm cvt_pk.
//  - step: Fv = exp2(ac4) once (16 trans, t-invariant); inner element =
//    rcp(fma(E,F,1)) -- removes 160 exp2 + 160 add per step per wave.

#define DEVFN __device__ __forceinline__

typedef __attribute__((ext_vector_type(8))) short short8;
typedef __attribute__((ext_vector_type(4))) float f32x4;
typedef __attribute__((ext_vector_type(4))) int int4v;

DEVFN unsigned bfr(float f) {  // f32 -> bf16 bits, round-to-nearest-even
  unsigned u = __float_as_uint(f);
  return (u + 0x7fffu + ((u >> 16) & 1u)) >> 16;
}
DEVFN unsigned pk2(float lo, float hi) { return bfr(lo) | (bfr(hi) << 16); }
// HW packed f32->bf16 (RTNE): dst.lo = bf16(lo), dst.hi = bf16(hi)
// NOTE: do NOT feed v_exp/v_rcp results directly into this asm (trans
// wait-state hazard not guaranteed for INLINEASM consumers) -- use pk2.
DEVFN unsigned cpk(float lo, float hi) {
  unsigned r;
  asm("v_cvt_pk_bf16_f32 %0, %1, %2" : "=v"(r) : "v"(lo), "v"(hi));
  return r;
}
DEVFN float ulo(unsigned p) { return __uint_as_float(p << 16); }
DEVFN float uhi(unsigned p) { return __uint_as_float(p & 0xffff0000u); }

// AGPR pinning: cold per-lane state lives in the otherwise-idle AGPR half.
DEVFN void awr(unsigned &a, unsigned v) {
  asm("v_accvgpr_write_b32 %0, %1" : "=a"(a) : "v"(v));
}
DEVFN unsigned ard(const unsigned &a) {
  unsigned v;
  asm("v_accvgpr_read_b32 %0, %1" : "=v"(v) : "a"(a));
  return v;
}

// 16-lane all-reduce sum, pure VALU (DPP), no LGKM traffic.
template <int CTRL>
DEVFN float dppadd(float v) {
  int t = __builtin_amdgcn_update_dpp(0, __float_as_int(v), CTRL, 0xf, 0xf, true);
  return v + __int_as_float(t);
}
DEVFN float sum16(float v) {
  v = dppadd<0xB1>(v);   // quad_perm(1,0,3,2)
  v = dppadd<0x4E>(v);   // quad_perm(2,3,0,1)
  v = dppadd<0x124>(v);  // row_ror:4
  v = dppadd<0x128>(v);  // row_ror:8
  return v;
}

// wave-internal LDS fence (cross-lane exchange within one wave).
DEVFN void lds_fence() {
  __builtin_amdgcn_wave_barrier();
  asm volatile("s_waitcnt lgkmcnt(0)" ::: "memory");
  __builtin_amdgcn_wave_barrier();
}

#define MFMA(a, b, c) __builtin_amdgcn_mfma_f32_16x16x32_bf16((a), (b), (c), 0, 0, 0)
#define EXP2(x) __builtin_amdgcn_exp2f(x)
#define RCP(x)  __builtin_amdgcn_rcpf(x)

// ---- LDS layout (bytes) ----
#define OFF_BHCT 0       // [64][136] bf16: W1_hc rows (e) x (j=0..127), *2log2e
#define OFF_BHHT 17408   // [256][72] bf16: W_hh rows (i) x (h), gate-scaled
#define OFF_BENC 54272   // [64][72]  bf16: W1_enc rows (e) x (d), *2log2e
#define OFF_BPRJ 63488   // [16][72]  bf16: n<5: fc_w[n][0:64]; n in 8..12: fco_w[n-8][64:128]
#define OFF_BIH  65792   // [256][40] bf16: W_ih gate-scaled in cols 0..4, zeros 5..31
#define OFF_BGC  86272   // [256]     f32 : (b_ih+b_hh) gate-scaled
#define OFF_FCO  87296   // [5][64]   f32 : fco_w[:, :64]
#define OFF_PW   88576   // per-wave regions
#define PWSZ     8832    //   +0: SCR [16][136] bf16 (x-tile staging, then hc)
                         //   +4352: YH [16][50] f32 (y tile, then yproj in place)
                         //   +7552: YTA [16][40] bf16 (y_tilde in A-layout)
#define SMEM_BYTES (OFF_PW + 8 * PWSZ)  // 159232

__global__ __launch_bounds__(512, 2) void attn_dec(
    const float* __restrict__ xg,   const float* __restrict__ yg,
    const float* __restrict__ h0,   const float* __restrict__ c0,
    const float* __restrict__ w1,   const float* __restrict__ b1g,
    const float* __restrict__ w2g,  const float* __restrict__ b2g,
    const float* __restrict__ wihg, const float* __restrict__ whhg,
    const float* __restrict__ bihg, const float* __restrict__ bhhg,
    const float* __restrict__ fcwg, const float* __restrict__ fcbg,
    const float* __restrict__ fcowg, const float* __restrict__ fcobg,
    float* __restrict__ outg) {
  (void)b2g;  // constant across t -> softmax-invariant
  extern __shared__ char smem[];
  unsigned short* BHCT = (unsigned short*)(smem + OFF_BHCT);
  unsigned short* BHHT = (unsigned short*)(smem + OFF_BHHT);
  unsigned short* BENC = (unsigned short*)(smem + OFF_BENC);
  unsigned short* BPRJ = (unsigned short*)(smem + OFF_BPRJ);
  unsigned short* BIH  = (unsigned short*)(smem + OFF_BIH);
  float* BGC  = (float*)(smem + OFF_BGC);
  float* FCOL = (float*)(smem + OFF_FCO);

  const int tid = threadIdx.x;
  const int wave = tid >> 6, lane = tid & 63;
  const int q = lane >> 4, m = lane & 15;
  const int rb = blockIdx.x * 128 + wave * 16;

  const float S2  = 2.88539008177792681f;   // 2*log2(e)
  const float NL  = -1.44269504088896341f;  // -log2(e)
  const float L2E = 1.44269504088896341f;

  unsigned short* SCR = (unsigned short*)(smem + OFF_PW + wave * PWSZ);
  float* YH = (float*)(smem + OFF_PW + wave * PWSZ + 4352);
  unsigned short* YTA = (unsigned short*)(smem + OFF_PW + wave * PWSZ + 7552);

  // ---------- cooperative shared-weight staging ----------
  for (int idx = tid; idx < 64 * 192; idx += 512) {
    int e = idx / 192, j = idx - e * 192;
    float v = w1[idx] * S2;
    if (j < 128) BHCT[e * 136 + j] = (unsigned short)bfr(v);
    else         BENC[e * 72 + (j - 128)] = (unsigned short)bfr(v);
  }
  for (int idx = tid; idx < 256 * 64; idx += 512) {
    int i = idx >> 6;
    float s = (i >= 128 && i < 192) ? S2 : NL;
    BHHT[i * 72 + (idx & 63)] = (unsigned short)bfr(whhg[idx] * s);
  }
  for (int idx = tid; idx < 16 * 64; idx += 512) {
    int n = idx >> 6, d = idx & 63;
    float v = 0.f;
    if (n < 5) v = fcwg[n * 69 + d];
    else if (n >= 8 && n < 13) v = fcowg[(n - 8) * 128 + 64 + d];
    BPRJ[n * 72 + d] = (unsigned short)bfr(v);
  }
  for (int idx = tid; idx < 256 * 32; idx += 512) {
    int n = idx >> 5, k = idx & 31;
    float s = (n >= 128 && n < 192) ? S2 : NL;
    float v = (k < 5) ? wihg[n * 5 + k] * s : 0.f;
    BIH[n * 40 + k] = (unsigned short)bfr(v);
  }
  for (int idx = tid; idx < 256; idx += 512) {
    float s = (idx >= 128 && idx < 192) ? S2 : NL;
    BGC[idx] = (bihg[idx] + bhhg[idx]) * s;
  }
  for (int idx = tid; idx < 5 * 64; idx += 512) {
    int d = idx >> 6, h = idx & 63;
    FCOL[idx] = fcowg[d * 128 + h];
  }
  __syncthreads();

  // ---------- per-wave: YH tile + YTA zero ----------
  for (int idx = lane; idx < 800; idx += 64) {
    int r = idx / 50, c = idx - r * 50;
    YH[idx] = yg[(size_t)(rb + r) * 50 + c];
  }
  for (int idx = lane; idx < 512; idx += 64)
    YTA[(idx >> 5) * 40 + (idx & 31)] = 0;
  lds_fence();

  // ---------- y-projection hoist: YH[row][t*5+n] <- fcb[n] + sum_j fcw[n][64+j]*y ----------
  {
    float fw[5][5], fb5[5];
#pragma unroll
    for (int n = 0; n < 5; ++n) {
      fb5[n] = fcbg[n];
#pragma unroll
      for (int j = 0; j < 5; ++j) fw[n][j] = fcwg[n * 69 + 64 + j];
    }
    for (int idx = lane; idx < 160; idx += 64) {
      int row = idx / 10, t = idx - row * 10;
      float yv[5];
#pragma unroll
      for (int j = 0; j < 5; ++j) yv[j] = YH[row * 50 + t * 5 + j];
#pragma unroll
      for (int n = 0; n < 5; ++n) {
        float v = fb5[n];
#pragma unroll
        for (int j = 0; j < 5; ++j) v = fmaf(fw[n][j], yv[j], v);
        YH[row * 50 + t * 5 + n] = v;
      }
    }
  }

  // ---------- per-lane constants ----------
  float b1e[4], w2n[4];
#pragma unroll
  for (int et = 0; et < 4; ++et) {
    b1e[et] = b1g[et * 16 + m] * S2;
    // score fold: p' accumulates (-2*w*log2e)*rcp(E*F+1); the constant
    // sum_e w*log2e part of w*tanh is global -> cancels in softmax.
    w2n[et] = w2g[et * 16 + m] * (-2.f * L2E);
  }
  const int mc = (m < 5) ? m : 4;
  const float fcobv = fcobg[mc];
  float bgr[16];  // hoisted gate biases: bgr[hg*4+g] = BGC[g*64+hg*16+m]
#pragma unroll
  for (int hg = 0; hg < 4; ++hg)
#pragma unroll
    for (int g = 0; g < 4; ++g) bgr[hg * 4 + g] = BGC[g * 64 + hg * 16 + m];

  // ---------- pre-loop: E = exp2(enc_proj*2log2e) + xf/xo projections -> AGPRs ----------
  unsigned ep[10][4][2];  // [t][e-tile][row-pair] packed bf16 of exp2(ep)  (AGPR)
  unsigned xfo[10][2];    // [t][row-pair]: col m<5 -> xf_d; col 8..12 -> xo  (AGPR)
  {
    const int rl = lane >> 2, cc = lane & 3;
    const float4* xpb = (const float4*)(xg + (size_t)(rb + rl) * 640);
    float4 v0 = xpb[cc * 4 + 0], v1 = xpb[cc * 4 + 1],
           v2 = xpb[cc * 4 + 2], v3 = xpb[cc * 4 + 3];
#pragma unroll
    for (int t = 0; t < 10; ++t) {
      lds_fence();  // WAR vs previous iteration's A-frag reads
      int4v d0, d1;
      d0.x = (int)cpk(v0.x, v0.y); d0.y = (int)cpk(v0.z, v0.w);
      d0.z = (int)cpk(v1.x, v1.y); d0.w = (int)cpk(v1.z, v1.w);
      d1.x = (int)cpk(v2.x, v2.y); d1.y = (int)cpk(v2.z, v2.w);
      d1.z = (int)cpk(v3.x, v3.y); d1.w = (int)cpk(v3.z, v3.w);
      *(int4v*)(SCR + rl * 72 + cc * 16) = d0;
      *(int4v*)(SCR + rl * 72 + cc * 16 + 8) = d1;
      lds_fence();
      if (t < 9) {  // software pipeline: next x-tile loads fly under the MFMAs
        v0 = xpb[(t + 1) * 16 + cc * 4 + 0];
        v1 = xpb[(t + 1) * 16 + cc * 4 + 1];
        v2 = xpb[(t + 1) * 16 + cc * 4 + 2];
        v3 = xpb[(t + 1) * 16 + cc * 4 + 3];
      }
      short8 xa0 = *(const short8*)(SCR + m * 72 + q * 8);
      short8 xa1 = *(const short8*)(SCR + m * 72 + 32 + q * 8);
#pragma unroll
      for (int et = 0; et < 4; ++et) {
        f32x4 acc = {0.f, 0.f, 0.f, 0.f};
        const unsigned short* bp = BENC + (et * 16 + m) * 72 + q * 8;
        acc = MFMA(xa0, *(const short8*)bp, acc);
        acc = MFMA(xa1, *(const short8*)(bp + 32), acc);
        // store E = exp2(ep); SOFTWARE pk2 so the trans results are consumed
        // by compiler-generated VALU (hazard-safe), not inline asm.
        awr(ep[t][et][0], pk2(EXP2(acc[0]), EXP2(acc[1])));
        awr(ep[t][et][1], pk2(EXP2(acc[2]), EXP2(acc[3])));
      }
      {
        f32x4 acc = {0.f, 0.f, 0.f, 0.f};
        const unsigned short* bp = BPRJ + m * 72 + q * 8;
        acc = MFMA(xa0, *(const short8*)bp, acc);
        acc = MFMA(xa1, *(const short8*)(bp + 32), acc);
        awr(xfo[t][0], cpk(acc[0], acc[1]));
        awr(xfo[t][1], cpk(acc[2], acc[3]));
      }
    }
  }

  // ---------- init state: ct f32 regs; [ht|ct] bf16 in SCR ----------
  float ctr[16];  // [hg*4 + r]
  lds_fence();
#pragma unroll
  for (int hg = 0; hg < 4; ++hg)
#pragma unroll
    for (int r = 0; r < 4; ++r) {
      int row = q * 4 + r, h = hg * 16 + m;
      float hv = h0[(size_t)(rb + row) * 64 + h];
      float cv = c0[(size_t)(rb + row) * 64 + h];
      ctr[hg * 4 + r] = cv;
      unsigned pk = cpk(hv, cv);
      SCR[row * 136 + h] = (unsigned short)pk;
      SCR[row * 136 + 64 + h] = (unsigned short)(pk >> 16);
    }
  lds_fence();

  // ---------- step loop ----------
  float yc[4] = {0.f, 0.f, 0.f, 0.f};
#pragma unroll 1
  for (int s = 0; s < 10; ++s) {
    // A) attn matvec: [ht|ct] @ W1_hc^T (+b1 folded into acc init)
    short8 fa0 = *(const short8*)(SCR + m * 136 + q * 8);
    short8 fa1 = *(const short8*)(SCR + m * 136 + 32 + q * 8);
    short8 fa2 = *(const short8*)(SCR + m * 136 + 64 + q * 8);
    short8 fa3 = *(const short8*)(SCR + m * 136 + 96 + q * 8);
    f32x4 ac4[4];
#pragma unroll
    for (int et = 0; et < 4; ++et) {
      f32x4 acc = {b1e[et], b1e[et], b1e[et], b1e[et]};
      const unsigned short* bp = BHCT + (et * 16 + m) * 136 + q * 8;
      acc = MFMA(fa0, *(const short8*)bp, acc);
      acc = MFMA(fa1, *(const short8*)(bp + 32), acc);
      acc = MFMA(fa2, *(const short8*)(bp + 64), acc);
      acc = MFMA(fa3, *(const short8*)(bp + 96), acc);
      ac4[et] = acc;
    }
    // F-factors: exp2(ac4) once per step (t-invariant); consumed only by
    // compiler fmaf (trans hazard handled by compiler).
    float Fv[4][4];
#pragma unroll
    for (int et = 0; et < 4; ++et)
#pragma unroll
      for (int r = 0; r < 4; ++r) Fv[et][r] = EXP2(ac4[et][r]);
    // B/C/D) scores + online (no-max) softmax + context contraction.
    // p' = sum_e (-2 w log2e) * rcp(E*F + 1), E = exp2(ep), F = exp2(ac);
    // dropped constant sum_e w is softmax-invariant. exp2(p') f32-safe.
    float sm0 = 0.f, sm1 = 0.f, sm2 = 0.f, sm3 = 0.f;
    float cx0 = 0.f, cx1 = 0.f, cx2 = 0.f, cx3 = 0.f;
#pragma unroll
    for (int t = 0; t < 10; ++t) {
      float p0 = 0.f, p1 = 0.f, p2 = 0.f, p3 = 0.f;
#pragma unroll
      for (int et = 0; et < 4; ++et) {
        unsigned plo = ard(ep[t][et][0]), phi = ard(ep[t][et][1]);
        float r0 = RCP(fmaf(ulo(plo), Fv[et][0], 1.f));
        float r1 = RCP(fmaf(uhi(plo), Fv[et][1], 1.f));
        float r2 = RCP(fmaf(ulo(phi), Fv[et][2], 1.f));
        float r3 = RCP(fmaf(uhi(phi), Fv[et][3], 1.f));
        float w = w2n[et];
        p0 = fmaf(w, r0, p0); p1 = fmaf(w, r1, p1);
        p2 = fmaf(w, r2, p2); p3 = fmaf(w, r3, p3);
      }
      p0 = sum16(p0); p1 = sum16(p1); p2 = sum16(p2); p3 = sum16(p3);
      float e0 = EXP2(p0);
      float e1 = EXP2(p1);
      float e2 = EXP2(p2);
      float e3 = EXP2(p3);
      sm0 += e0; sm1 += e1; sm2 += e2; sm3 += e3;
      unsigned xl = ard(xfo[t][0]), xh = ard(xfo[t][1]);
      cx0 = fmaf(e0, ulo(xl), cx0);
      cx1 = fmaf(e1, uhi(xl), cx1);
      cx2 = fmaf(e2, ulo(xh), cx2);
      cx3 = fmaf(e3, uhi(xh), cx3);
    }
    yc[0] = cx0 * RCP(sm0);
    yc[1] = cx1 * RCP(sm1);
    yc[2] = cx2 * RCP(sm2);
    yc[3] = cx3 * RCP(sm3);
    // E) y_tilde -> YTA (A-layout rows, bf16); y-part precomputed in YH
#pragma unroll
    for (int r = 0; r < 4; ++r) {
      int row = q * 4 + r;
      float v = yc[r] + YH[row * 50 + s * 5 + mc];
      if (m < 5) YTA[row * 40 + m] = (unsigned short)cpk(v, v);
    }
    lds_fence();
    // F/G) gates = [ht] @ W_hh^T + [y_tilde] @ W_ih^T (+bias in acc init); LSTM update
    short8 ay = *(const short8*)(YTA + m * 40 + q * 8);
#pragma unroll
    for (int hg = 0; hg < 4; ++hg) {
      float ga[4][4];
#pragma unroll
      for (int g = 0; g < 4; ++g) {
        int n = g * 64 + hg * 16 + m;
        float bg = bgr[hg * 4 + g];
        f32x4 acc = {bg, bg, bg, bg};
        const unsigned short* bp = BHHT + n * 72 + q * 8;
        acc = MFMA(fa0, *(const short8*)bp, acc);
        acc = MFMA(fa1, *(const short8*)(bp + 32), acc);
        acc = MFMA(ay, *(const short8*)(BIH + n * 40 + q * 8), acc);
        ga[g][0] = acc[0]; ga[g][1] = acc[1]; ga[g][2] = acc[2]; ga[g][3] = acc[3];
      }
#pragma unroll
      for (int r = 0; r < 4; ++r) {
        float iv = RCP(1.f + EXP2(ga[0][r]));
        float fv = RCP(1.f + EXP2(ga[1][r]));
        float gv = fmaf(-2.f, RCP(EXP2(ga[2][r]) + 1.f), 1.f);
        float ov = RCP(1.f + EXP2(ga[3][r]));
        float c = fmaf(fv, ctr[hg * 4 + r], iv * gv);
        ctr[hg * 4 + r] = c;
        float th = fmaf(-2.f, RCP(EXP2(c * S2) + 1.f), 1.f);
        float hv = ov * th;
        int row = q * 4 + r, h = hg * 16 + m;
        unsigned pk = cpk(hv, c);
        SCR[row * 136 + h] = (unsigned short)pk;
        SCR[row * 136 + 64 + h] = (unsigned short)(pk >> 16);
      }
    }
    lds_fence();
  }

  // ---------- output: out = [ht, context] @ fco_w^T + fco_b ----------
#pragma unroll
  for (int r = 0; r < 4; ++r) {
    int row = q * 4 + r;
    float sum = fcobv + __shfl(yc[r], (lane & 48) + 8 + mc);
#pragma unroll
    for (int hq = 0; hq < 8; ++hq) {
      int4v hv = *(const int4v*)(SCR + row * 136 + hq * 8);
      const float* fp = FCOL + mc * 64 + hq * 8;
      sum += fp[0] * ulo((unsigned)hv.x) + fp[1] * uhi((unsigned)hv.x)
           + fp[2] * ulo((unsigned)hv.y) + fp[3] * uhi((unsigned)hv.y)
           + fp[4] * ulo((unsigned)hv.z) + fp[5] * uhi((unsigned)hv.z)
           + fp[6] * ulo((unsigned)hv.w) + fp[7] * uhi((unsigned)hv.w);
    }
    if (m < 5) outg[(size_t)(rb + row) * 5 + m] = sum;
  }
}

extern "C" void kernel_launch(void* const* d_in, const int* in_sizes, int n_in,
                              void* d_out, int out_size, void* d_ws, size_t ws_size,
                              hipStream_t stream) {
  (void)in_sizes; (void)n_in; (void)d_ws; (void)ws_size; (void)out_size;
  (void)hipFuncSetAttribute((const void*)attn_dec,
                            hipFuncAttributeMaxDynamicSharedMemorySize, SMEM_BYTES);
  attn_dec<<<dim3(512), dim3(512), SMEM_BYTES, stream>>>(
      (const float*)d_in[0], (const float*)d_in[1], (const float*)d_in[2],
      (const float*)d_in[3], (const float*)d_in[4], (const float*)d_in[5],
      (const float*)d_in[6], (const float*)d_in[7], (const float*)d_in[8],
      (const float*)d_in[9], (const float*)d_in[10], (const float*)d_in[11],
      (const float*)d_in[12], (const float*)d_in[13], (const float*)d_in[14],
      (const float*)d_in[15], (float*)d_out);
}

// Round 5
// 506.513 us; speedup vs baseline: 1.6289x; 1.0405x over previous
//
#include <hip/hip_runtime.h>

// AttentionDecoder: B=65536, T=10, E=64, H=64, D=5
// One wave owns 16 batch rows end-to-end; no inter-wave sync in the step loop.
// R2/R3: ep/xfo pinned in AGPRs (spill fix); online no-max softmax; DPP
// allreduce; y_tilde via 3rd MFMA; biases folded into MFMA acc init.
// R4: score fold; v_cvt_pk_bf16_f32; y-proj hoist; preloop prefetch.
// R5 (FAILED NaN): EXP2 -> inline-asm cvt_pk (trans->INLINEASM hazard).
// R6 (REGRESSED): gacc hoist spilled (228+64 > 256 unified regs). Lessons:
// occupancy register-locked at 2 waves/SIMD; budget every hoist.
// R7 (WIN 378->339us): hazard-safe exp2 factorization (E=exp2(ep) packed via
// software pk2; step inner = rcp(fma(E,F,1))). BUT: WRITE_SIZE 3.3->24.8MB
// = Fv[16] pushed past the register ceiling -> small per-step spill.
// R8 (this round): register-pressure relief, zero arithmetic change --
//  ctr[16] (LSTM cell state) and the 16 gate biases move to AGPRs via
//  v_accvgpr pinning (AGPR 100->132, VGPR demand -32). Kills the spill and
//  frees ~32 VGPRs so the independent softmax t-chains / LSTM cell-chains
//  can pipeline deeper. +~48 cheap accvgpr moves per step.

#define DEVFN __device__ __forceinline__

typedef __attribute__((ext_vector_type(8))) short short8;
typedef __attribute__((ext_vector_type(4))) float f32x4;
typedef __attribute__((ext_vector_type(4))) int int4v;

DEVFN unsigned bfr(float f) {  // f32 -> bf16 bits, round-to-nearest-even
  unsigned u = __float_as_uint(f);
  return (u + 0x7fffu + ((u >> 16) & 1u)) >> 16;
}
DEVFN unsigned pk2(float lo, float hi) { return bfr(lo) | (bfr(hi) << 16); }
// HW packed f32->bf16 (RTNE): dst.lo = bf16(lo), dst.hi = bf16(hi)
// NOTE: do NOT feed v_exp/v_rcp results directly into this asm (trans
// wait-state hazard not guaranteed for INLINEASM consumers) -- use pk2.
DEVFN unsigned cpk(float lo, float hi) {
  unsigned r;
  asm("v_cvt_pk_bf16_f32 %0, %1, %2" : "=v"(r) : "v"(lo), "v"(hi));
  return r;
}
DEVFN float ulo(unsigned p) { return __uint_as_float(p << 16); }
DEVFN float uhi(unsigned p) { return __uint_as_float(p & 0xffff0000u); }

// AGPR pinning: cold per-lane state lives in the otherwise-idle AGPR half.
DEVFN void awr(unsigned &a, unsigned v) {
  asm("v_accvgpr_write_b32 %0, %1" : "=a"(a) : "v"(v));
}
DEVFN unsigned ard(const unsigned &a) {
  unsigned v;
  asm("v_accvgpr_read_b32 %0, %1" : "=v"(v) : "a"(a));
  return v;
}
DEVFN void awrf(unsigned &a, float v) { awr(a, __float_as_uint(v)); }
DEVFN float ardf(const unsigned &a) { return __uint_as_float(ard(a)); }

// 16-lane all-reduce sum, pure VALU (DPP), no LGKM traffic.
template <int CTRL>
DEVFN float dppadd(float v) {
  int t = __builtin_amdgcn_update_dpp(0, __float_as_int(v), CTRL, 0xf, 0xf, true);
  return v + __int_as_float(t);
}
DEVFN float sum16(float v) {
  v = dppadd<0xB1>(v);   // quad_perm(1,0,3,2)
  v = dppadd<0x4E>(v);   // quad_perm(2,3,0,1)
  v = dppadd<0x124>(v);  // row_ror:4
  v = dppadd<0x128>(v);  // row_ror:8
  return v;
}

// wave-internal LDS fence (cross-lane exchange within one wave).
DEVFN void lds_fence() {
  __builtin_amdgcn_wave_barrier();
  asm volatile("s_waitcnt lgkmcnt(0)" ::: "memory");
  __builtin_amdgcn_wave_barrier();
}

#define MFMA(a, b, c) __builtin_amdgcn_mfma_f32_16x16x32_bf16((a), (b), (c), 0, 0, 0)
#define EXP2(x) __builtin_amdgcn_exp2f(x)
#define RCP(x)  __builtin_amdgcn_rcpf(x)

// ---- LDS layout (bytes) ----
#define OFF_BHCT 0       // [64][136] bf16: W1_hc rows (e) x (j=0..127), *2log2e
#define OFF_BHHT 17408   // [256][72] bf16: W_hh rows (i) x (h), gate-scaled
#define OFF_BENC 54272   // [64][72]  bf16: W1_enc rows (e) x (d), *2log2e
#define OFF_BPRJ 63488   // [16][72]  bf16: n<5: fc_w[n][0:64]; n in 8..12: fco_w[n-8][64:128]
#define OFF_BIH  65792   // [256][40] bf16: W_ih gate-scaled in cols 0..4, zeros 5..31
#define OFF_BGC  86272   // [256]     f32 : (b_ih+b_hh) gate-scaled
#define OFF_FCO  87296   // [5][64]   f32 : fco_w[:, :64]
#define OFF_PW   88576   // per-wave regions
#define PWSZ     8832    //   +0: SCR [16][136] bf16 (x-tile staging, then hc)
                         //   +4352: YH [16][50] f32 (y tile, then yproj in place)
                         //   +7552: YTA [16][40] bf16 (y_tilde in A-layout)
#define SMEM_BYTES (OFF_PW + 8 * PWSZ)  // 159232

__global__ __launch_bounds__(512, 2) void attn_dec(
    const float* __restrict__ xg,   const float* __restrict__ yg,
    const float* __restrict__ h0,   const float* __restrict__ c0,
    const float* __restrict__ w1,   const float* __restrict__ b1g,
    const float* __restrict__ w2g,  const float* __restrict__ b2g,
    const float* __restrict__ wihg, const float* __restrict__ whhg,
    const float* __restrict__ bihg, const float* __restrict__ bhhg,
    const float* __restrict__ fcwg, const float* __restrict__ fcbg,
    const float* __restrict__ fcowg, const float* __restrict__ fcobg,
    float* __restrict__ outg) {
  (void)b2g;  // constant across t -> softmax-invariant
  extern __shared__ char smem[];
  unsigned short* BHCT = (unsigned short*)(smem + OFF_BHCT);
  unsigned short* BHHT = (unsigned short*)(smem + OFF_BHHT);
  unsigned short* BENC = (unsigned short*)(smem + OFF_BENC);
  unsigned short* BPRJ = (unsigned short*)(smem + OFF_BPRJ);
  unsigned short* BIH  = (unsigned short*)(smem + OFF_BIH);
  float* BGC  = (float*)(smem + OFF_BGC);
  float* FCOL = (float*)(smem + OFF_FCO);

  const int tid = threadIdx.x;
  const int wave = tid >> 6, lane = tid & 63;
  const int q = lane >> 4, m = lane & 15;
  const int rb = blockIdx.x * 128 + wave * 16;

  const float S2  = 2.88539008177792681f;   // 2*log2(e)
  const float NL  = -1.44269504088896341f;  // -log2(e)
  const float L2E = 1.44269504088896341f;

  unsigned short* SCR = (unsigned short*)(smem + OFF_PW + wave * PWSZ);
  float* YH = (float*)(smem + OFF_PW + wave * PWSZ + 4352);
  unsigned short* YTA = (unsigned short*)(smem + OFF_PW + wave * PWSZ + 7552);

  // ---------- cooperative shared-weight staging ----------
  for (int idx = tid; idx < 64 * 192; idx += 512) {
    int e = idx / 192, j = idx - e * 192;
    float v = w1[idx] * S2;
    if (j < 128) BHCT[e * 136 + j] = (unsigned short)bfr(v);
    else         BENC[e * 72 + (j - 128)] = (unsigned short)bfr(v);
  }
  for (int idx = tid; idx < 256 * 64; idx += 512) {
    int i = idx >> 6;
    float s = (i >= 128 && i < 192) ? S2 : NL;
    BHHT[i * 72 + (idx & 63)] = (unsigned short)bfr(whhg[idx] * s);
  }
  for (int idx = tid; idx < 16 * 64; idx += 512) {
    int n = idx >> 6, d = idx & 63;
    float v = 0.f;
    if (n < 5) v = fcwg[n * 69 + d];
    else if (n >= 8 && n < 13) v = fcowg[(n - 8) * 128 + 64 + d];
    BPRJ[n * 72 + d] = (unsigned short)bfr(v);
  }
  for (int idx = tid; idx < 256 * 32; idx += 512) {
    int n = idx >> 5, k = idx & 31;
    float s = (n >= 128 && n < 192) ? S2 : NL;
    float v = (k < 5) ? wihg[n * 5 + k] * s : 0.f;
    BIH[n * 40 + k] = (unsigned short)bfr(v);
  }
  for (int idx = tid; idx < 256; idx += 512) {
    float s = (idx >= 128 && idx < 192) ? S2 : NL;
    BGC[idx] = (bihg[idx] + bhhg[idx]) * s;
  }
  for (int idx = tid; idx < 5 * 64; idx += 512) {
    int d = idx >> 6, h = idx & 63;
    FCOL[idx] = fcowg[d * 128 + h];
  }
  __syncthreads();

  // ---------- per-wave: YH tile + YTA zero ----------
  for (int idx = lane; idx < 800; idx += 64) {
    int r = idx / 50, c = idx - r * 50;
    YH[idx] = yg[(size_t)(rb + r) * 50 + c];
  }
  for (int idx = lane; idx < 512; idx += 64)
    YTA[(idx >> 5) * 40 + (idx & 31)] = 0;
  lds_fence();

  // ---------- y-projection hoist: YH[row][t*5+n] <- fcb[n] + sum_j fcw[n][64+j]*y ----------
  {
    float fw[5][5], fb5[5];
#pragma unroll
    for (int n = 0; n < 5; ++n) {
      fb5[n] = fcbg[n];
#pragma unroll
      for (int j = 0; j < 5; ++j) fw[n][j] = fcwg[n * 69 + 64 + j];
    }
    for (int idx = lane; idx < 160; idx += 64) {
      int row = idx / 10, t = idx - row * 10;
      float yv[5];
#pragma unroll
      for (int j = 0; j < 5; ++j) yv[j] = YH[row * 50 + t * 5 + j];
#pragma unroll
      for (int n = 0; n < 5; ++n) {
        float v = fb5[n];
#pragma unroll
        for (int j = 0; j < 5; ++j) v = fmaf(fw[n][j], yv[j], v);
        YH[row * 50 + t * 5 + n] = v;
      }
    }
  }

  // ---------- per-lane constants ----------
  float b1e[4], w2n[4];
#pragma unroll
  for (int et = 0; et < 4; ++et) {
    b1e[et] = b1g[et * 16 + m] * S2;
    // score fold: p' accumulates (-2*w*log2e)*rcp(E*F+1); the constant
    // sum_e w*log2e part of w*tanh is global -> cancels in softmax.
    w2n[et] = w2g[et * 16 + m] * (-2.f * L2E);
  }
  const int mc = (m < 5) ? m : 4;
  const float fcobv = fcobg[mc];
  // gate biases -> AGPRs (cold state; read 1x/step each)
  unsigned abgr[16];
#pragma unroll
  for (int hg = 0; hg < 4; ++hg)
#pragma unroll
    for (int g = 0; g < 4; ++g) awrf(abgr[hg * 4 + g], BGC[g * 64 + hg * 16 + m]);

  // ---------- pre-loop: E = exp2(enc_proj*2log2e) + xf/xo projections -> AGPRs ----------
  unsigned ep[10][4][2];  // [t][e-tile][row-pair] packed bf16 of exp2(ep)  (AGPR)
  unsigned xfo[10][2];    // [t][row-pair]: col m<5 -> xf_d; col 8..12 -> xo  (AGPR)
  {
    const int rl = lane >> 2, cc = lane & 3;
    const float4* xpb = (const float4*)(xg + (size_t)(rb + rl) * 640);
    float4 v0 = xpb[cc * 4 + 0], v1 = xpb[cc * 4 + 1],
           v2 = xpb[cc * 4 + 2], v3 = xpb[cc * 4 + 3];
#pragma unroll
    for (int t = 0; t < 10; ++t) {
      lds_fence();  // WAR vs previous iteration's A-frag reads
      int4v d0, d1;
      d0.x = (int)cpk(v0.x, v0.y); d0.y = (int)cpk(v0.z, v0.w);
      d0.z = (int)cpk(v1.x, v1.y); d0.w = (int)cpk(v1.z, v1.w);
      d1.x = (int)cpk(v2.x, v2.y); d1.y = (int)cpk(v2.z, v2.w);
      d1.z = (int)cpk(v3.x, v3.y); d1.w = (int)cpk(v3.z, v3.w);
      *(int4v*)(SCR + rl * 72 + cc * 16) = d0;
      *(int4v*)(SCR + rl * 72 + cc * 16 + 8) = d1;
      lds_fence();
      if (t < 9) {  // software pipeline: next x-tile loads fly under the MFMAs
        v0 = xpb[(t + 1) * 16 + cc * 4 + 0];
        v1 = xpb[(t + 1) * 16 + cc * 4 + 1];
        v2 = xpb[(t + 1) * 16 + cc * 4 + 2];
        v3 = xpb[(t + 1) * 16 + cc * 4 + 3];
      }
      short8 xa0 = *(const short8*)(SCR + m * 72 + q * 8);
      short8 xa1 = *(const short8*)(SCR + m * 72 + 32 + q * 8);
#pragma unroll
      for (int et = 0; et < 4; ++et) {
        f32x4 acc = {0.f, 0.f, 0.f, 0.f};
        const unsigned short* bp = BENC + (et * 16 + m) * 72 + q * 8;
        acc = MFMA(xa0, *(const short8*)bp, acc);
        acc = MFMA(xa1, *(const short8*)(bp + 32), acc);
        // store E = exp2(ep); SOFTWARE pk2 so the trans results are consumed
        // by compiler-generated VALU (hazard-safe), not inline asm.
        awr(ep[t][et][0], pk2(EXP2(acc[0]), EXP2(acc[1])));
        awr(ep[t][et][1], pk2(EXP2(acc[2]), EXP2(acc[3])));
      }
      {
        f32x4 acc = {0.f, 0.f, 0.f, 0.f};
        const unsigned short* bp = BPRJ + m * 72 + q * 8;
        acc = MFMA(xa0, *(const short8*)bp, acc);
        acc = MFMA(xa1, *(const short8*)(bp + 32), acc);
        awr(xfo[t][0], cpk(acc[0], acc[1]));
        awr(xfo[t][1], cpk(acc[2], acc[3]));
      }
    }
  }

  // ---------- init state: ct -> AGPRs; [ht|ct] bf16 in SCR ----------
  unsigned actr[16];  // LSTM cell state, AGPR-pinned  [hg*4 + r]
  lds_fence();
#pragma unroll
  for (int hg = 0; hg < 4; ++hg)
#pragma unroll
    for (int r = 0; r < 4; ++r) {
      int row = q * 4 + r, h = hg * 16 + m;
      float hv = h0[(size_t)(rb + row) * 64 + h];
      float cv = c0[(size_t)(rb + row) * 64 + h];
      awrf(actr[hg * 4 + r], cv);
      unsigned pk = cpk(hv, cv);
      SCR[row * 136 + h] = (unsigned short)pk;
      SCR[row * 136 + 64 + h] = (unsigned short)(pk >> 16);
    }
  lds_fence();

  // ---------- step loop ----------
  float yc[4] = {0.f, 0.f, 0.f, 0.f};
#pragma unroll 1
  for (int s = 0; s < 10; ++s) {
    // A) attn matvec: [ht|ct] @ W1_hc^T (+b1 folded into acc init)
    short8 fa0 = *(const short8*)(SCR + m * 136 + q * 8);
    short8 fa1 = *(const short8*)(SCR + m * 136 + 32 + q * 8);
    short8 fa2 = *(const short8*)(SCR + m * 136 + 64 + q * 8);
    short8 fa3 = *(const short8*)(SCR + m * 136 + 96 + q * 8);
    f32x4 ac4[4];
#pragma unroll
    for (int et = 0; et < 4; ++et) {
      f32x4 acc = {b1e[et], b1e[et], b1e[et], b1e[et]};
      const unsigned short* bp = BHCT + (et * 16 + m) * 136 + q * 8;
      acc = MFMA(fa0, *(const short8*)bp, acc);
      acc = MFMA(fa1, *(const short8*)(bp + 32), acc);
      acc = MFMA(fa2, *(const short8*)(bp + 64), acc);
      acc = MFMA(fa3, *(const short8*)(bp + 96), acc);
      ac4[et] = acc;
    }
    // F-factors: exp2(ac4) once per step (t-invariant); consumed only by
    // compiler fmaf (trans hazard handled by compiler).
    float Fv[4][4];
#pragma unroll
    for (int et = 0; et < 4; ++et)
#pragma unroll
      for (int r = 0; r < 4; ++r) Fv[et][r] = EXP2(ac4[et][r]);
    // B/C/D) scores + online (no-max) softmax + context contraction.
    // p' = sum_e (-2 w log2e) * rcp(E*F + 1), E = exp2(ep), F = exp2(ac);
    // dropped constant sum_e w is softmax-invariant. exp2(p') f32-safe.
    float sm0 = 0.f, sm1 = 0.f, sm2 = 0.f, sm3 = 0.f;
    float cx0 = 0.f, cx1 = 0.f, cx2 = 0.f, cx3 = 0.f;
#pragma unroll
    for (int t = 0; t < 10; ++t) {
      float p0 = 0.f, p1 = 0.f, p2 = 0.f, p3 = 0.f;
#pragma unroll
      for (int et = 0; et < 4; ++et) {
        unsigned plo = ard(ep[t][et][0]), phi = ard(ep[t][et][1]);
        float r0 = RCP(fmaf(ulo(plo), Fv[et][0], 1.f));
        float r1 = RCP(fmaf(uhi(plo), Fv[et][1], 1.f));
        float r2 = RCP(fmaf(ulo(phi), Fv[et][2], 1.f));
        float r3 = RCP(fmaf(uhi(phi), Fv[et][3], 1.f));
        float w = w2n[et];
        p0 = fmaf(w, r0, p0); p1 = fmaf(w, r1, p1);
        p2 = fmaf(w, r2, p2); p3 = fmaf(w, r3, p3);
      }
      p0 = sum16(p0); p1 = sum16(p1); p2 = sum16(p2); p3 = sum16(p3);
      float e0 = EXP2(p0);
      float e1 = EXP2(p1);
      float e2 = EXP2(p2);
      float e3 = EXP2(p3);
      sm0 += e0; sm1 += e1; sm2 += e2; sm3 += e3;
      unsigned xl = ard(xfo[t][0]), xh = ard(xfo[t][1]);
      cx0 = fmaf(e0, ulo(xl), cx0);
      cx1 = fmaf(e1, uhi(xl), cx1);
      cx2 = fmaf(e2, ulo(xh), cx2);
      cx3 = fmaf(e3, uhi(xh), cx3);
    }
    yc[0] = cx0 * RCP(sm0);
    yc[1] = cx1 * RCP(sm1);
    yc[2] = cx2 * RCP(sm2);
    yc[3] = cx3 * RCP(sm3);
    // E) y_tilde -> YTA (A-layout rows, bf16); y-part precomputed in YH
#pragma unroll
    for (int r = 0; r < 4; ++r) {
      int row = q * 4 + r;
      float v = yc[r] + YH[row * 50 + s * 5 + mc];
      if (m < 5) YTA[row * 40 + m] = (unsigned short)cpk(v, v);
    }
    lds_fence();
    // F/G) gates = [ht] @ W_hh^T + [y_tilde] @ W_ih^T (+bias in acc init); LSTM update
    short8 ay = *(const short8*)(YTA + m * 40 + q * 8);
#pragma unroll
    for (int hg = 0; hg < 4; ++hg) {
      float ga[4][4];
#pragma unroll
      for (int g = 0; g < 4; ++g) {
        int n = g * 64 + hg * 16 + m;
        float bg = ardf(abgr[hg * 4 + g]);
        f32x4 acc = {bg, bg, bg, bg};
        const unsigned short* bp = BHHT + n * 72 + q * 8;
        acc = MFMA(fa0, *(const short8*)bp, acc);
        acc = MFMA(fa1, *(const short8*)(bp + 32), acc);
        acc = MFMA(ay, *(const short8*)(BIH + n * 40 + q * 8), acc);
        ga[g][0] = acc[0]; ga[g][1] = acc[1]; ga[g][2] = acc[2]; ga[g][3] = acc[3];
      }
#pragma unroll
      for (int r = 0; r < 4; ++r) {
        float iv = RCP(1.f + EXP2(ga[0][r]));
        float fv = RCP(1.f + EXP2(ga[1][r]));
        float gv = fmaf(-2.f, RCP(EXP2(ga[2][r]) + 1.f), 1.f);
        float ov = RCP(1.f + EXP2(ga[3][r]));
        float c = fmaf(fv, ardf(actr[hg * 4 + r]), iv * gv);
        awrf(actr[hg * 4 + r], c);
        float th = fmaf(-2.f, RCP(EXP2(c * S2) + 1.f), 1.f);
        float hv = ov * th;
        int row = q * 4 + r, h = hg * 16 + m;
        unsigned pk = cpk(hv, c);
        SCR[row * 136 + h] = (unsigned short)pk;
        SCR[row * 136 + 64 + h] = (unsigned short)(pk >> 16);
      }
    }
    lds_fence();
  }

  // ---------- output: out = [ht, context] @ fco_w^T + fco_b ----------
#pragma unroll
  for (int r = 0; r < 4; ++r) {
    int row = q * 4 + r;
    float sum = fcobv + __shfl(yc[r], (lane & 48) + 8 + mc);
#pragma unroll
    for (int hq = 0; hq < 8; ++hq) {
      int4v hv = *(const int4v*)(SCR + row * 136 + hq * 8);
      const float* fp = FCOL + mc * 64 + hq * 8;
      sum += fp[0] * ulo((unsigned)hv.x) + fp[1] * uhi((unsigned)hv.x)
           + fp[2] * ulo((unsigned)hv.y) + fp[3] * uhi((unsigned)hv.y)
           + fp[4] * ulo((unsigned)hv.z) + fp[5] * uhi((unsigned)hv.z)
           + fp[6] * ulo((unsigned)hv.w) + fp[7] * uhi((unsigned)hv.w);
    }
    if (m < 5) outg[(size_t)(rb + row) * 5 + m] = sum;
  }
}

extern "C" void kernel_launch(void* const* d_in, const int* in_sizes, int n_in,
                              void* d_out, int out_size, void* d_ws, size_t ws_size,
                              hipStream_t stream) {
  (void)in_sizes; (void)n_in; (void)d_ws; (void)ws_size; (void)out_size;
  (void)hipFuncSetAttribute((const void*)attn_dec,
                            hipFuncAttributeMaxDynamicSharedMemorySize, SMEM_BYTES);
  attn_dec<<<dim3(512), dim3(512), SMEM_BYTES, stream>>>(
      (const float*)d_in[0], (const float*)d_in[1], (const float*)d_in[2],
      (const float*)d_in[3], (const float*)d_in[4], (const float*)d_in[5],
      (const float*)d_in[6], (const float*)d_in[7], (const float*)d_in[8],
      (const float*)d_in[9], (const float*)d_in[10], (const float*)d_in[11],
      (const float*)d_in[12], (const float*)d_in[13], (const float*)d_in[14],
      (const float*)d_in[15], (float*)d_out);
}

// Round 6
// 502.849 us; speedup vs baseline: 1.6408x; 1.0073x over previous
//
#include <hip/hip_runtime.h>

// AttentionDecoder: B=65536, T=10, E=64, H=64, D=5
// One wave owns 16 batch rows end-to-end; no inter-wave sync in the step loop.
// R2/R3: ep/xfo pinned in AGPRs; online no-max softmax; y_tilde via 3rd MFMA.
// R4: score fold; v_cvt_pk_bf16_f32; y-proj hoist; preloop prefetch.
// R5 (FAILED NaN): EXP2 -> inline-asm cvt_pk (trans->INLINEASM hazard).
// R6 (REGRESSED): gacc hoist spilled (>256 unified regs @ 2 waves/SIMD).
// R7 (WIN ->339): hazard-safe exp2 factorization: E=exp2(ep), rcp(fma(E,F,1)).
// R8 (WIN ->318): ctr/gate-bias -> AGPRs; spill killed (WRITE 24.8->1.3MB).
// R9 (this round): latency-chain attack at fixed occupancy --
//  (a) FLIPPED softmax: swap MFMA operands (same regs/LDS reads! A/B frags
//      are mirrored) so scores come out C[e][row]. Row-reduction becomes
//      in-lane tree + 2 shfl_xor(16,32) instead of 4x sum16 (32 DPP ops);
//      exp2 4->1 per t; sm rcp 4->1 per step. b1 folded into stored E.
//      w2/b1 become per-lane 16-vectors; epilogues re-addressed (no shfl).
//  (b) preloop loads x DIRECTLY in fragment layout (lane(q,m): row m,
//      cols q*8) -- SCR staging transpose + 2 lds_fences/iter removed.

#define DEVFN __device__ __forceinline__

typedef __attribute__((ext_vector_type(8))) short short8;
typedef __attribute__((ext_vector_type(4))) float f32x4;
typedef __attribute__((ext_vector_type(4))) int int4v;

DEVFN unsigned bfr(float f) {  // f32 -> bf16 bits, round-to-nearest-even
  unsigned u = __float_as_uint(f);
  return (u + 0x7fffu + ((u >> 16) & 1u)) >> 16;
}
DEVFN unsigned pk2(float lo, float hi) { return bfr(lo) | (bfr(hi) << 16); }
// HW packed f32->bf16 (RTNE). NOTE: never feed v_exp/v_rcp results directly
// into this asm (trans->INLINEASM wait-state hazard, R5) -- use pk2 there.
DEVFN unsigned cpk(float lo, float hi) {
  unsigned r;
  asm("v_cvt_pk_bf16_f32 %0, %1, %2" : "=v"(r) : "v"(lo), "v"(hi));
  return r;
}
DEVFN float ulo(unsigned p) { return __uint_as_float(p << 16); }
DEVFN float uhi(unsigned p) { return __uint_as_float(p & 0xffff0000u); }

// AGPR pinning: cold per-lane state lives in the otherwise-idle AGPR half.
DEVFN void awr(unsigned &a, unsigned v) {
  asm("v_accvgpr_write_b32 %0, %1" : "=a"(a) : "v"(v));
}
DEVFN unsigned ard(const unsigned &a) {
  unsigned v;
  asm("v_accvgpr_read_b32 %0, %1" : "=v"(v) : "a"(a));
  return v;
}
DEVFN void awrf(unsigned &a, float v) { awr(a, __float_as_uint(v)); }
DEVFN float ardf(const unsigned &a) { return __uint_as_float(ard(a)); }

// wave-internal LDS fence (cross-lane exchange within one wave).
DEVFN void lds_fence() {
  __builtin_amdgcn_wave_barrier();
  asm volatile("s_waitcnt lgkmcnt(0)" ::: "memory");
  __builtin_amdgcn_wave_barrier();
}

#define MFMA(a, b, c) __builtin_amdgcn_mfma_f32_16x16x32_bf16((a), (b), (c), 0, 0, 0)
#define EXP2(x) __builtin_amdgcn_exp2f(x)
#define RCP(x)  __builtin_amdgcn_rcpf(x)

// ---- LDS layout (bytes) ----
#define OFF_BHCT 0       // [64][136] bf16: W1_hc rows (e) x (j=0..127), *2log2e
#define OFF_BHHT 17408   // [256][72] bf16: W_hh rows (i) x (h), gate-scaled
#define OFF_BENC 54272   // [64][72]  bf16: W1_enc rows (e) x (d), *2log2e
#define OFF_BPRJ 63488   // [16][72]  bf16: n<5: fc_w[n][0:64]; n in 8..12: fco_w[n-8][64:128]
#define OFF_BIH  65792   // [256][40] bf16: W_ih gate-scaled in cols 0..4, zeros 5..31
#define OFF_BGC  86272   // [256]     f32 : (b_ih+b_hh) gate-scaled
#define OFF_FCO  87296   // [5][64]   f32 : fco_w[:, :64]
#define OFF_PW   88576   // per-wave regions
#define PWSZ     8832    //   +0: SCR [16][136] bf16 (hc state)
                         //   +4352: YH [16][50] f32 (y tile, then yproj in place)
                         //   +7552: YTA [16][40] bf16 (y_tilde in A-layout)
#define SMEM_BYTES (OFF_PW + 8 * PWSZ)  // 159232

__global__ __launch_bounds__(512, 2) void attn_dec(
    const float* __restrict__ xg,   const float* __restrict__ yg,
    const float* __restrict__ h0,   const float* __restrict__ c0,
    const float* __restrict__ w1,   const float* __restrict__ b1g,
    const float* __restrict__ w2g,  const float* __restrict__ b2g,
    const float* __restrict__ wihg, const float* __restrict__ whhg,
    const float* __restrict__ bihg, const float* __restrict__ bhhg,
    const float* __restrict__ fcwg, const float* __restrict__ fcbg,
    const float* __restrict__ fcowg, const float* __restrict__ fcobg,
    float* __restrict__ outg) {
  (void)b2g;  // constant across t -> softmax-invariant
  extern __shared__ char smem[];
  unsigned short* BHCT = (unsigned short*)(smem + OFF_BHCT);
  unsigned short* BHHT = (unsigned short*)(smem + OFF_BHHT);
  unsigned short* BENC = (unsigned short*)(smem + OFF_BENC);
  unsigned short* BPRJ = (unsigned short*)(smem + OFF_BPRJ);
  unsigned short* BIH  = (unsigned short*)(smem + OFF_BIH);
  float* BGC  = (float*)(smem + OFF_BGC);
  float* FCOL = (float*)(smem + OFF_FCO);

  const int tid = threadIdx.x;
  const int wave = tid >> 6, lane = tid & 63;
  const int q = lane >> 4, m = lane & 15;
  const int rb = blockIdx.x * 128 + wave * 16;

  const float S2  = 2.88539008177792681f;   // 2*log2(e)
  const float NL  = -1.44269504088896341f;  // -log2(e)
  const float L2E = 1.44269504088896341f;

  unsigned short* SCR = (unsigned short*)(smem + OFF_PW + wave * PWSZ);
  float* YH = (float*)(smem + OFF_PW + wave * PWSZ + 4352);
  unsigned short* YTA = (unsigned short*)(smem + OFF_PW + wave * PWSZ + 7552);

  // ---------- cooperative shared-weight staging ----------
  for (int idx = tid; idx < 64 * 192; idx += 512) {
    int e = idx / 192, j = idx - e * 192;
    float v = w1[idx] * S2;
    if (j < 128) BHCT[e * 136 + j] = (unsigned short)bfr(v);
    else         BENC[e * 72 + (j - 128)] = (unsigned short)bfr(v);
  }
  for (int idx = tid; idx < 256 * 64; idx += 512) {
    int i = idx >> 6;
    float s = (i >= 128 && i < 192) ? S2 : NL;
    BHHT[i * 72 + (idx & 63)] = (unsigned short)bfr(whhg[idx] * s);
  }
  for (int idx = tid; idx < 16 * 64; idx += 512) {
    int n = idx >> 6, d = idx & 63;
    float v = 0.f;
    if (n < 5) v = fcwg[n * 69 + d];
    else if (n >= 8 && n < 13) v = fcowg[(n - 8) * 128 + 64 + d];
    BPRJ[n * 72 + d] = (unsigned short)bfr(v);
  }
  for (int idx = tid; idx < 256 * 32; idx += 512) {
    int n = idx >> 5, k = idx & 31;
    float s = (n >= 128 && n < 192) ? S2 : NL;
    float v = (k < 5) ? wihg[n * 5 + k] * s : 0.f;
    BIH[n * 40 + k] = (unsigned short)bfr(v);
  }
  for (int idx = tid; idx < 256; idx += 512) {
    float s = (idx >= 128 && idx < 192) ? S2 : NL;
    BGC[idx] = (bihg[idx] + bhhg[idx]) * s;
  }
  for (int idx = tid; idx < 5 * 64; idx += 512) {
    int d = idx >> 6, h = idx & 63;
    FCOL[idx] = fcowg[d * 128 + h];
  }
  __syncthreads();

  // ---------- per-wave: YH tile + YTA zero ----------
  for (int idx = lane; idx < 800; idx += 64) {
    int r = idx / 50, c = idx - r * 50;
    YH[idx] = yg[(size_t)(rb + r) * 50 + c];
  }
  for (int idx = lane; idx < 512; idx += 64)
    YTA[(idx >> 5) * 40 + (idx & 31)] = 0;
  lds_fence();

  // ---------- y-projection hoist: YH[row][t*5+n] <- fcb[n] + sum_j fcw[n][64+j]*y ----------
  {
    float fw[5][5], fb5[5];
#pragma unroll
    for (int n = 0; n < 5; ++n) {
      fb5[n] = fcbg[n];
#pragma unroll
      for (int j = 0; j < 5; ++j) fw[n][j] = fcwg[n * 69 + 64 + j];
    }
    for (int idx = lane; idx < 160; idx += 64) {
      int row = idx / 10, t = idx - row * 10;
      float yv[5];
#pragma unroll
      for (int j = 0; j < 5; ++j) yv[j] = YH[row * 50 + t * 5 + j];
#pragma unroll
      for (int n = 0; n < 5; ++n) {
        float v = fb5[n];
#pragma unroll
        for (int j = 0; j < 5; ++j) v = fmaf(fw[n][j], yv[j], v);
        YH[row * 50 + t * 5 + n] = v;
      }
    }
  }
  lds_fence();  // YH yproj writes -> cross-lane YH reads in step loop

  // ---------- per-lane constants (flipped layout: e = et*16 + q*4 + r) ----------
  float w2n[16];
#pragma unroll
  for (int et = 0; et < 4; ++et)
#pragma unroll
    for (int r = 0; r < 4; ++r)
      w2n[et * 4 + r] = w2g[et * 16 + q * 4 + r] * (-2.f * L2E);
  // gate biases -> AGPRs (cold state; read 1x/step each)
  unsigned abgr[16];
#pragma unroll
  for (int hg = 0; hg < 4; ++hg)
#pragma unroll
    for (int g = 0; g < 4; ++g) awrf(abgr[hg * 4 + g], BGC[g * 64 + hg * 16 + m]);

  // ---------- pre-loop: E = exp2(enc_proj + b1) + xf/xo projections -> AGPRs ----------
  // Flipped: MFMA(weight_frag, x_frag) -> C[e][row]; lane(q,m): row=m,
  // e = et*16 + q*4 + reg. x loaded DIRECTLY in B-frag layout (row m, cols q*8).
  unsigned ep[10][4][2];  // [t][et][pair] packed bf16 of exp2(ep+b1)  (AGPR)
  unsigned xfo[10][2];    // [t][pair]: slots d=q*4+r (d<5: fc_w-proj; 8..12: fco-proj)  (AGPR)
  {
    float b1v[16];
#pragma unroll
    for (int et = 0; et < 4; ++et)
#pragma unroll
      for (int r = 0; r < 4; ++r) b1v[et * 4 + r] = b1g[et * 16 + q * 4 + r] * S2;
    const float4* xpb = (const float4*)xg + (size_t)(rb + m) * 160 + q * 2;
    float4 v0 = xpb[0], v1 = xpb[1], v2 = xpb[8], v3 = xpb[9];
#pragma unroll
    for (int t = 0; t < 10; ++t) {
      int4v A0, A1;
      A0.x = (int)cpk(v0.x, v0.y); A0.y = (int)cpk(v0.z, v0.w);
      A0.z = (int)cpk(v1.x, v1.y); A0.w = (int)cpk(v1.z, v1.w);
      A1.x = (int)cpk(v2.x, v2.y); A1.y = (int)cpk(v2.z, v2.w);
      A1.z = (int)cpk(v3.x, v3.y); A1.w = (int)cpk(v3.z, v3.w);
      if (t < 9) {  // prefetch next t under the MFMAs/packing
        v0 = xpb[(t + 1) * 16 + 0]; v1 = xpb[(t + 1) * 16 + 1];
        v2 = xpb[(t + 1) * 16 + 8]; v3 = xpb[(t + 1) * 16 + 9];
      }
      short8 xa0 = *(const short8*)&A0;
      short8 xa1 = *(const short8*)&A1;
#pragma unroll
      for (int et = 0; et < 4; ++et) {
        f32x4 acc = {0.f, 0.f, 0.f, 0.f};
        const unsigned short* ap = BENC + (et * 16 + m) * 72 + q * 8;
        acc = MFMA(*(const short8*)ap, xa0, acc);
        acc = MFMA(*(const short8*)(ap + 32), xa1, acc);
        // E = exp2(ep + b1); SOFTWARE pk2 (trans results -> compiler VALU).
        awr(ep[t][et][0], pk2(EXP2(acc[0] + b1v[et * 4 + 0]),
                              EXP2(acc[1] + b1v[et * 4 + 1])));
        awr(ep[t][et][1], pk2(EXP2(acc[2] + b1v[et * 4 + 2]),
                              EXP2(acc[3] + b1v[et * 4 + 3])));
      }
      {
        f32x4 acc = {0.f, 0.f, 0.f, 0.f};
        const unsigned short* ap = BPRJ + m * 72 + q * 8;
        acc = MFMA(*(const short8*)ap, xa0, acc);
        acc = MFMA(*(const short8*)(ap + 32), xa1, acc);
        awr(xfo[t][0], cpk(acc[0], acc[1]));
        awr(xfo[t][1], cpk(acc[2], acc[3]));
      }
    }
  }

  // ---------- init state: ct -> AGPRs; [ht|ct] bf16 in SCR ----------
  unsigned actr[16];  // LSTM cell state, AGPR-pinned  [hg*4 + r]
  lds_fence();
#pragma unroll
  for (int hg = 0; hg < 4; ++hg)
#pragma unroll
    for (int r = 0; r < 4; ++r) {
      int row = q * 4 + r, h = hg * 16 + m;
      float hv = h0[(size_t)(rb + row) * 64 + h];
      float cv = c0[(size_t)(rb + row) * 64 + h];
      awrf(actr[hg * 4 + r], cv);
      unsigned pk = cpk(hv, cv);
      SCR[row * 136 + h] = (unsigned short)pk;
      SCR[row * 136 + 64 + h] = (unsigned short)(pk >> 16);
    }
  lds_fence();

  // ---------- step loop ----------
  float yc[4] = {0.f, 0.f, 0.f, 0.f};
#pragma unroll 1
  for (int s = 0; s < 10; ++s) {
    // A) flipped attn matvec: C'[e][row] = W1_hc @ [ht|ct]^T; same LDS reads,
    // operands swapped. Lane(q,m): row=m, e = et*16 + q*4 + reg.
    short8 fa0 = *(const short8*)(SCR + m * 136 + q * 8);
    short8 fa1 = *(const short8*)(SCR + m * 136 + 32 + q * 8);
    short8 fa2 = *(const short8*)(SCR + m * 136 + 64 + q * 8);
    short8 fa3 = *(const short8*)(SCR + m * 136 + 96 + q * 8);
    f32x4 ac4[4];
#pragma unroll
    for (int et = 0; et < 4; ++et) {
      f32x4 acc = {0.f, 0.f, 0.f, 0.f};
      const unsigned short* ap = BHCT + (et * 16 + m) * 136 + q * 8;
      acc = MFMA(*(const short8*)ap,        fa0, acc);
      acc = MFMA(*(const short8*)(ap + 32), fa1, acc);
      acc = MFMA(*(const short8*)(ap + 64), fa2, acc);
      acc = MFMA(*(const short8*)(ap + 96), fa3, acc);
      ac4[et] = acc;
    }
    // F-factors: exp2(ac) once per step (t-invariant), 16 per lane.
    float Fv[16];
#pragma unroll
    for (int et = 0; et < 4; ++et)
#pragma unroll
      for (int r = 0; r < 4; ++r) Fv[et * 4 + r] = EXP2(ac4[et][r]);
    // B/C/D) scores + online (no-max) softmax + context contraction.
    // Per lane: 16 e-terms of its row; in-lane tree + shfl_xor(16,32) reduce.
    float sm = 0.f;
    float cx0 = 0.f, cx1 = 0.f, cx2 = 0.f, cx3 = 0.f;
#pragma unroll
    for (int t = 0; t < 10; ++t) {
      float pe[4];
#pragma unroll
      for (int et = 0; et < 4; ++et) {
        unsigned plo = ard(ep[t][et][0]), phi = ard(ep[t][et][1]);
        float r0 = RCP(fmaf(ulo(plo), Fv[et * 4 + 0], 1.f));
        float r1 = RCP(fmaf(uhi(plo), Fv[et * 4 + 1], 1.f));
        float r2 = RCP(fmaf(ulo(phi), Fv[et * 4 + 2], 1.f));
        float r3 = RCP(fmaf(uhi(phi), Fv[et * 4 + 3], 1.f));
        float v = w2n[et * 4 + 0] * r0;
        v = fmaf(w2n[et * 4 + 1], r1, v);
        v = fmaf(w2n[et * 4 + 2], r2, v);
        v = fmaf(w2n[et * 4 + 3], r3, v);
        pe[et] = v;
      }
      float p = (pe[0] + pe[1]) + (pe[2] + pe[3]);
      p += __shfl_xor(p, 16);
      p += __shfl_xor(p, 32);
      float e0 = EXP2(p);
      sm += e0;
      unsigned xl = ard(xfo[t][0]), xh = ard(xfo[t][1]);
      cx0 = fmaf(e0, ulo(xl), cx0);
      cx1 = fmaf(e0, uhi(xl), cx1);
      cx2 = fmaf(e0, ulo(xh), cx2);
      cx3 = fmaf(e0, uhi(xh), cx3);
    }
    {
      float rs = RCP(sm);
      yc[0] = cx0 * rs; yc[1] = cx1 * rs; yc[2] = cx2 * rs; yc[3] = cx3 * rs;
    }
    // E) y_tilde -> YTA row m, col n = q*4+r (n<5); y-part precomputed in YH
#pragma unroll
    for (int r = 0; r < 4; ++r) {
      int n = q * 4 + r;
      if (n < 5) {
        float v = yc[r] + YH[m * 50 + s * 5 + n];
        YTA[m * 40 + n] = (unsigned short)cpk(v, v);
      }
    }
    lds_fence();
    // F/G) gates = [ht] @ W_hh^T + [y_tilde] @ W_ih^T (+bias in acc init); LSTM update
    short8 ay = *(const short8*)(YTA + m * 40 + q * 8);
#pragma unroll
    for (int hg = 0; hg < 4; ++hg) {
      float ga[4][4];
#pragma unroll
      for (int g = 0; g < 4; ++g) {
        int n = g * 64 + hg * 16 + m;
        float bg = ardf(abgr[hg * 4 + g]);
        f32x4 acc = {bg, bg, bg, bg};
        const unsigned short* bp = BHHT + n * 72 + q * 8;
        acc = MFMA(fa0, *(const short8*)bp, acc);
        acc = MFMA(fa1, *(const short8*)(bp + 32), acc);
        acc = MFMA(ay, *(const short8*)(BIH + n * 40 + q * 8), acc);
        ga[g][0] = acc[0]; ga[g][1] = acc[1]; ga[g][2] = acc[2]; ga[g][3] = acc[3];
      }
#pragma unroll
      for (int r = 0; r < 4; ++r) {
        float iv = RCP(1.f + EXP2(ga[0][r]));
        float fv = RCP(1.f + EXP2(ga[1][r]));
        float gv = fmaf(-2.f, RCP(EXP2(ga[2][r]) + 1.f), 1.f);
        float ov = RCP(1.f + EXP2(ga[3][r]));
        float c = fmaf(fv, ardf(actr[hg * 4 + r]), iv * gv);
        awrf(actr[hg * 4 + r], c);
        float th = fmaf(-2.f, RCP(EXP2(c * S2) + 1.f), 1.f);
        float hv = ov * th;
        int row = q * 4 + r, h = hg * 16 + m;
        unsigned pk = cpk(hv, c);
        SCR[row * 136 + h] = (unsigned short)pk;
        SCR[row * 136 + 64 + h] = (unsigned short)(pk >> 16);
      }
    }
    lds_fence();
  }

  // ---------- output: out[row=m][dd] for dd = q*4+r-8 in 0..4 ----------
  // yc slot d = q*4+r: d in 8..12 holds sum_t alpha_t * (fco_w[d-8][64:]@x_t)
#pragma unroll
  for (int r = 0; r < 4; ++r) {
    int dd = q * 4 + r - 8;
    if ((unsigned)dd < 5u) {
      float sum = fcobg[dd] + yc[r];
#pragma unroll
      for (int hq = 0; hq < 8; ++hq) {
        int4v hv = *(const int4v*)(SCR + m * 136 + hq * 8);
        const float* fp = FCOL + dd * 64 + hq * 8;
        sum += fp[0] * ulo((unsigned)hv.x) + fp[1] * uhi((unsigned)hv.x)
             + fp[2] * ulo((unsigned)hv.y) + fp[3] * uhi((unsigned)hv.y)
             + fp[4] * ulo((unsigned)hv.z) + fp[5] * uhi((unsigned)hv.z)
             + fp[6] * ulo((unsigned)hv.w) + fp[7] * uhi((unsigned)hv.w);
      }
      outg[(size_t)(rb + m) * 5 + dd] = sum;
    }
  }
}

extern "C" void kernel_launch(void* const* d_in, const int* in_sizes, int n_in,
                              void* d_out, int out_size, void* d_ws, size_t ws_size,
                              hipStream_t stream) {
  (void)in_sizes; (void)n_in; (void)d_ws; (void)ws_size; (void)out_size;
  (void)hipFuncSetAttribute((const void*)attn_dec,
                            hipFuncAttributeMaxDynamicSharedMemorySize, SMEM_BYTES);
  attn_dec<<<dim3(512), dim3(512), SMEM_BYTES, stream>>>(
      (const float*)d_in[0], (const float*)d_in[1], (const float*)d_in[2],
      (const float*)d_in[3], (const float*)d_in[4], (const float*)d_in[5],
      (const float*)d_in[6], (const float*)d_in[7], (const float*)d_in[8],
      (const float*)d_in[9], (const float*)d_in[10], (const float*)d_in[11],
      (const float*)d_in[12], (const float*)d_in[13], (const float*)d_in[14],
      (const float*)d_in[15], (float*)d_out);
}